// Round 16
// baseline (1510.997 us; speedup 1.0000x reference)
//
#include <hip/hip_runtime.h>
#include <hip/hip_bf16.h>
#include <cmath>

#define S_LEN 2048
#define DM 768
#define NH 12
#define DHEAD 64
#define FF_DIM 3072
#define NLAYERS 12
#define WIN 256

typedef __attribute__((ext_vector_type(4))) float f32x4;
typedef __attribute__((ext_vector_type(8))) short s16x8;
typedef __attribute__((ext_vector_type(4))) short s16x4;
typedef __attribute__((ext_vector_type(4))) float fragc;

// per-layer bf16 transposed-weight slab offsets (elems)
#define OFF_QKVT 0L
#define OFF_WOT  1769472L
#define OFF_W1T  2359296L
#define OFF_W2T  4718592L
#define WSLAB    7077888L

__device__ __forceinline__ float bf2f(ushort u) {
  union { unsigned u; float f; } v; v.u = ((unsigned)u) << 16; return v.f;
}
__device__ __forceinline__ ushort f2bf(float f) {
  union { float f; unsigned u; } v; v.f = f;
  unsigned r = v.u + 0x7fffu + ((v.u >> 16) & 1u);
  return (ushort)(r >> 16);
}

typedef __attribute__((address_space(1))) const void GVp;
typedef __attribute__((address_space(3))) void LVp;
__device__ __forceinline__ void gload16(const void* g, void* l) {
  __builtin_amdgcn_global_load_lds((GVp*)g, (LVp*)l, 16, 0, 0);
}

// GEMM: BM(=64) x BN tile, BK=64, double-buffered LDS prefetch (1 barrier/
// k-step), XOR-swizzled LDS (pre-swizzled global source, linear gload_lds
// dest), 1D grid with bijective XCD swizzle. 4 waves; wave owns (BM/2)x(BN/2).
// Grid sizing rule: keep total blocks a multiple of 256 (CU count).
// A [M][K] bf16 (K-contig); B [N][K] bf16 (K-contig).
// EPI: 0 = (+bias)->bf16 ; 2 = gelu(x+bias)->bf16 ; 3 = x(+bias+res on z0)->f32
// SPLIT: gridDim.z==2, z halves of K; z=0 -> C0 (bias+res), z=1 -> C1 plain.
// VOUT: QKV only — V-tiles (nt >= 1536/BN) transpose via smem -> coalesced vbT.
template<int EPI, int BM, int BN, bool SPLIT, bool VOUT>
__global__ __launch_bounds__(256) void gemm_t(
    const ushort* __restrict__ A0, int lda,
    const ushort* __restrict__ B0, int ldb,
    void* __restrict__ C0, void* __restrict__ C1, int ldc,
    const float* __restrict__ bias0,
    const float* __restrict__ res0,
    int Kdim,                       // per-z K length
    ushort* __restrict__ vbTp)
{
  constexpr int MF = BM / 32;        // 2
  constexpr int NF = BN / 32;        // 2,3,4
  constexpr int MT = S_LEN / BM;     // 32
  __shared__ ushort As[2][BM * 64];
  __shared__ ushort Bs[2][BN * 64];

  const int tid  = threadIdx.x;
  const int lane = tid & 63;
  const int wave = tid >> 6;
  const int z    = SPLIT ? blockIdx.z : 0;
  const int koff = z * Kdim;

  const int nwg = gridDim.x;         // % 8 == 0
  const int o   = blockIdx.x;
  const int id2 = (o & 7) * (nwg >> 3) + (o >> 3);
  const int mt  = id2 % MT;
  const int nt  = id2 / MT;

  const long aoff = (long)mt * BM * lda;
  const long boff = (long)nt * BN * ldb;
  const long coff = (long)mt * BM * ldc + (long)nt * BN;
  const float* bias = bias0 ? bias0 + nt * BN : nullptr;

  fragc acc[MF][NF] = {};
  const int l15 = lane & 15;
  const int g   = lane >> 4;
  const int rx  = l15 & 7;
  const int MR0 = (wave & 1) * (BM / 2);
  const int NC0 = (wave >> 1) * (BN / 2);
  const int srow = lane >> 3;                 // 0..7 within 8-row chunk
  const int scol = ((lane & 7) ^ srow) * 8;   // pre-swizzled source col (elems)

  auto stage = [&](int buf, int k0) {
    #pragma unroll
    for (int j = 0; j < BM / 32; j++) {
      int c = wave * (BM / 32) + j;
      gload16(A0 + aoff + (long)(c * 8 + srow) * lda + k0 + scol,
              (char*)&As[buf][0] + c * 1024);
    }
    #pragma unroll
    for (int j = 0; j < BN / 32; j++) {
      int c = wave * (BN / 32) + j;
      gload16(B0 + boff + (long)(c * 8 + srow) * ldb + k0 + scol,
              (char*)&Bs[buf][0] + c * 1024);
    }
  };

  stage(0, koff);
  __syncthreads();
  int cur = 0;
  for (int k0 = koff; k0 < koff + Kdim; k0 += 64) {
    if (k0 + 64 < koff + Kdim) stage(cur ^ 1, k0 + 64);   // prefetch next
    s16x8 afr[MF][2], bfr[NF][2];
    #pragma unroll
    for (int ks = 0; ks < 2; ks++) {
      #pragma unroll
      for (int mi = 0; mi < MF; mi++)
        afr[mi][ks] = *(const s16x8*)((const char*)&As[cur][0] +
                      (MR0 + mi * 16 + l15) * 128 + (((ks * 4 + g) ^ rx) << 4));
      #pragma unroll
      for (int ni = 0; ni < NF; ni++)
        bfr[ni][ks] = *(const s16x8*)((const char*)&Bs[cur][0] +
                      (NC0 + ni * 16 + l15) * 128 + (((ks * 4 + g) ^ rx) << 4));
    }
    #pragma unroll
    for (int ks = 0; ks < 2; ks++)
      #pragma unroll
      for (int mi = 0; mi < MF; mi++)
        #pragma unroll
        for (int ni = 0; ni < NF; ni++)
          acc[mi][ni] = __builtin_amdgcn_mfma_f32_16x16x32_bf16(afr[mi][ks], bfr[ni][ks], acc[mi][ni], 0, 0, 0);
    __syncthreads();
    cur ^= 1;
  }

  const int rb = g * 4;

  if (VOUT && nt >= 1536 / BN) {
    // V tile: transpose in smem (alias As+Bs), then coalesced vbT stores
    ushort (*Vt)[72] = (ushort(*)[72])&As[0][0];   // BN x 72 x 2B
    #pragma unroll
    for (int mi = 0; mi < MF; mi++)
    #pragma unroll
    for (int ni = 0; ni < NF; ni++) {
      const int row0 = MR0 + mi * 16 + rb;
      const int col  = NC0 + ni * 16 + l15;
      s16x4 pk;
      #pragma unroll
      for (int r = 0; r < 4; r++) pk[r] = (short)f2bf(acc[mi][ni][r] + bias[col]);
      *(s16x4*)&Vt[col][row0] = pk;
    }
    __syncthreads();
    if (tid < BN * 2) {
      const int d  = tid >> 1;
      const int th = (tid & 1) * 32;
      ushort* gdst = vbTp + (size_t)(nt * BN - 1536 + d) * S_LEN + mt * BM + th;
      #pragma unroll
      for (int j = 0; j < 4; j++)
        *(s16x8*)(gdst + j * 8) = *(const s16x8*)&Vt[d][th + j * 8];
    }
    return;
  }

  ushort* Cb = (ushort*)C0;
  float*  Cf = (float*)(z == 0 ? C0 : C1);
  #pragma unroll
  for (int mi = 0; mi < MF; mi++)
  #pragma unroll
  for (int ni = 0; ni < NF; ni++) {
    const int row0 = MR0 + mi * 16 + rb;
    const int col  = NC0 + ni * 16 + l15;
    #pragma unroll
    for (int r = 0; r < 4; r++) {
      long ci = coff + (long)(row0 + r) * ldc + col;
      float v = acc[mi][ni][r];
      if (EPI == 0) {
        if (bias) v += bias[col];
        Cb[ci] = f2bf(v);
      } else if (EPI == 2) {
        v += bias[col];
        v = 0.5f * v * (1.0f + erff(v * 0.70710678118654752f));
        Cb[ci] = f2bf(v);
      } else {
        if (z == 0) v += bias[col] + res0[ci];
        Cf[ci] = v;
      }
    }
  }
}

// ---------------- fused sliding-window flash attention ----------------
// 1D grid 384 with XCD swizzle; 4 waves x 16 queries. K double-buffered;
// V staged for kt+1 after the PV barrier. Q frags hoisted.
__global__ __launch_bounds__(256) void attn_k(
    const ushort* __restrict__ qkvb,   // [2048][2304]
    const ushort* __restrict__ vbT,    // [12*64][2048]
    const int*    __restrict__ am,
    ushort*       __restrict__ aob)    // [2048][768]
{
  __shared__ ushort Qs[64 * 64];
  __shared__ ushort Ks[2][128 * 64];
  __shared__ ushort Vs[64 * 128];
  __shared__ ushort Ps[4][16 * 128];
  __shared__ float  ambias[768];

  const int tid  = threadIdx.x;
  const int lane = tid & 63;
  const int w    = tid >> 6;
  const int l15  = lane & 15;
  const int g    = lane >> 4;
  const int o    = blockIdx.x;
  const int id2  = (o & 7) * 48 + (o >> 3);   // 384 = 8 * 48
  const int h    = id2 >> 5;
  const int q0   = (id2 & 31) * 64;
  const int korigin = (q0 >> 8) * 256 - WIN;
  const int q    = q0 + w * 16 + l15;

  auto stageK = [&](int buf, int kt) {
    int tok0 = korigin + kt * 128;
    #pragma unroll
    for (int j = 0; j < 4; j++) {
      int c = w * 4 + j;
      int stored = c * 1024 + lane * 16;
      int row = stored >> 7;
      int within = (stored & 127) ^ ((row & 7) << 4);
      int tok = tok0 + row;
      tok = tok < 0 ? 0 : (tok > S_LEN - 1 ? S_LEN - 1 : tok);
      gload16(qkvb + (size_t)tok * 2304 + DM + h * DHEAD + (within >> 1),
              (char*)&Ks[buf][0] + stored);
    }
  };
  auto stageV = [&](int kt) {
    int tok0 = korigin + kt * 128;
    #pragma unroll
    for (int j = 0; j < 4; j++) {
      int c = w * 4 + j;
      int stored = c * 1024 + lane * 16;
      int row = stored >> 8;
      int within = (stored & 255) ^ ((row & 7) << 4);
      int tok = tok0 + (within >> 1);
      tok = tok < 0 ? 0 : (tok > S_LEN - 8 ? S_LEN - 8 : tok);
      gload16(vbT + ((size_t)h * DHEAD + row) * S_LEN + tok,
              (char*)Vs + stored);
    }
  };

  #pragma unroll
  for (int j = 0; j < 2; j++) {
    int c = w * 2 + j;
    int stored = c * 1024 + lane * 16;
    int row = stored >> 7;
    int within = (stored & 127) ^ ((row & 7) << 4);
    gload16(qkvb + (size_t)(q0 + row) * 2304 + h * DHEAD + (within >> 1),
            (char*)Qs + stored);
  }
  for (int j = tid; j < 768; j += 256) {
    int tok = korigin + j;
    bool ok = (tok >= 0) && (tok < S_LEN) && (am[tok] != 0);
    ambias[j] = ok ? 0.0f : -1e30f;
  }

  const int lo = q0 - WIN < 0 ? 0 : q0 - WIN;
  const int hi = (q0 + 63 + WIN > S_LEN - 1) ? S_LEN - 1 : q0 + 63 + WIN;
  const int kt_start = (lo - korigin) >> 7;
  const int kt_end   = (hi - korigin) >> 7;

  stageK(0, kt_start);
  stageV(kt_start);
  __syncthreads();

  s16x8 qf[2];
  #pragma unroll
  for (int ks = 0; ks < 2; ks++)
    qf[ks] = *(const s16x8*)((const char*)Qs + (w * 16 + l15) * 128 +
                             ((g * 16 + ks * 64) ^ ((l15 & 7) << 4)));

  f32x4 ot[4] = {};
  float m = -1e20f, l = 0.0f;
  int cur = 0;

  for (int kt = kt_start; kt <= kt_end; kt++) {
    if (kt < kt_end) stageK(cur ^ 1, kt + 1);

    f32x4 st[8] = {};
    __builtin_amdgcn_s_setprio(1);
    #pragma unroll
    for (int ks = 0; ks < 2; ks++) {
      #pragma unroll
      for (int mi = 0; mi < 8; mi++) {
        int row = mi * 16 + l15;
        s16x8 af = *(const s16x8*)((const char*)&Ks[cur][0] + row * 128 +
                                   ((g * 16 + ks * 64) ^ ((row & 7) << 4)));
        st[mi] = __builtin_amdgcn_mfma_f32_16x16x32_bf16(af, qf[ks], st[mi], 0, 0, 0);
      }
    }
    __builtin_amdgcn_s_setprio(0);

    float mx = -1e30f;
    float sv[8][4];
    #pragma unroll
    for (int mi = 0; mi < 8; mi++)
      #pragma unroll
      for (int r = 0; r < 4; r++) {
        int kw  = kt * 128 + mi * 16 + g * 4 + r;
        int tok = korigin + kw;
        float s = st[mi][r] * 0.125f + ambias[kw];
        bool band = (tok >= q - WIN) && (tok <= q + WIN);
        s = band ? s : -1e30f;
        sv[mi][r] = s;
        mx = fmaxf(mx, s);
      }
    mx = fmaxf(mx, __shfl_xor(mx, 16));
    mx = fmaxf(mx, __shfl_xor(mx, 32));

    float m_new = fmaxf(fmaxf(m, mx), -1e20f);
    float sf = __expf(m - m_new);
    float rs = 0.0f;
    #pragma unroll
    for (int mi = 0; mi < 8; mi++) {
      s16x4 pk;
      #pragma unroll
      for (int r = 0; r < 4; r++) {
        float p = __expf(sv[mi][r] - m_new);
        rs += p;
        pk[r] = (short)f2bf(p);
      }
      *(s16x4*)((char*)&Ps[w][0] + l15 * 256 + ((mi * 32 + g * 8) ^ ((l15 & 7) << 4))) = pk;
    }
    rs += __shfl_xor(rs, 16);
    rs += __shfl_xor(rs, 32);
    l = l * sf + rs;
    m = m_new;
    #pragma unroll
    for (int mi = 0; mi < 4; mi++)
      #pragma unroll
      for (int r = 0; r < 4; r++) ot[mi][r] *= sf;

    __syncthreads();   // B1: V(cur) + K(next) drained

    __builtin_amdgcn_s_setprio(1);
    #pragma unroll
    for (int ks = 0; ks < 4; ks++) {
      s16x8 pf = *(const s16x8*)((const char*)&Ps[w][0] + l15 * 256 +
                                 ((ks * 64 + g * 16) ^ ((l15 & 7) << 4)));
      #pragma unroll
      for (int mi = 0; mi < 4; mi++) {
        int row = mi * 16 + l15;
        s16x8 vf = *(const s16x8*)((const char*)Vs + row * 256 +
                                   ((ks * 64 + g * 16) ^ ((row & 7) << 4)));
        ot[mi] = __builtin_amdgcn_mfma_f32_16x16x32_bf16(vf, pf, ot[mi], 0, 0, 0);
      }
    }
    __builtin_amdgcn_s_setprio(0);
    __syncthreads();   // B2: all waves done with Vs

    if (kt < kt_end) stageV(kt + 1);
    cur ^= 1;
  }

  float inv = l > 0.0f ? 1.0f / l : 0.0f;
  #pragma unroll
  for (int mi = 0; mi < 4; mi++) {
    s16x4 oo;
    #pragma unroll
    for (int r = 0; r < 4; r++) oo[r] = (short)f2bf(ot[mi][r] * inv);
    *(s16x4*)(aob + (size_t)q * DM + h * DHEAD + mi * 16 + g * 4) = oo;
  }
}

// unified transpose-convert with WRITE COMBINING: each block owns a
// 64-row x 256-k strip. Four 64-k subphases convert f32->bf16 into
// tileT[64][257] (odd stride: subphase scalar writes exactly 2-way banks);
// register-pipelined (rA/rB named sets), ONE barrier; store phase writes
// 512B contiguous per output row (4x bigger DRAM bursts than before).
// grid: (432, NLAYERS)
__global__ __launch_bounds__(256) void cvtall_k(
    const float* __restrict__ Wq, const float* __restrict__ Wk,
    const float* __restrict__ Wv, const float* __restrict__ Wo,
    const float* __restrict__ W1, const float* __restrict__ W2,
    ushort* __restrict__ wT)
{
  __shared__ ushort tileT[64][257];
  const int tid = threadIdx.x;
  const size_t L = blockIdx.y;
  int t = blockIdx.x;
  const float* src; ushort* dst; int N, K, ng, ky, dnoff = 0;
  if (t < 144) {
    int region = t / 36, tt = t % 36;
    N = DM; K = DM; ng = tt % 12; ky = tt / 12;              // 12 n x 3 ky
    src = (region == 0 ? Wq : region == 1 ? Wk : region == 2 ? Wv : Wo) + L * DM * DM;
    if (region < 3) { dst = wT + L * WSLAB + OFF_QKVT; dnoff = region * DM; }
    else            { dst = wT + L * WSLAB + OFF_WOT; }
  } else if (t < 288) {
    int tt = t - 144;
    N = FF_DIM; K = DM; ng = tt % 48; ky = tt / 48;          // 48 n x 3 ky
    src = W1 + L * DM * FF_DIM;
    dst = wT + L * WSLAB + OFF_W1T;
  } else {
    int tt = t - 288;
    N = DM; K = FF_DIM; ng = tt % 12; ky = tt / 12;          // 12 n x 12 ky
    src = W2 + L * DM * FF_DIM;
    dst = wT + L * WSLAB + OFF_W2T;
  }
  const int k0t = ky * 256;
  const int n0  = ng * 64;

  const int krel = tid >> 2;          // 0..63 source k-row within subphase
  const int nseg = (tid & 3) * 16;    // 16-col segment within 64 n

  f32x4 rA[4], rB[4];
  auto gread = [&](f32x4* r, int sub) {
    const float* s = src + (long)(k0t + sub * 64 + krel) * N + n0 + nseg;
    #pragma unroll
    for (int i = 0; i < 4; i++) r[i] = *(const f32x4*)(s + i * 4);
  };
  auto lput = [&](const f32x4* r, int sub) {
    #pragma unroll
    for (int i = 0; i < 4; i++)
      #pragma unroll
      for (int cc = 0; cc < 4; cc++)
        tileT[nseg + i * 4 + cc][sub * 64 + krel] = f2bf(r[i][cc]);
  };

  gread(rA, 0);
  gread(rB, 1); lput(rA, 0);
  gread(rA, 2); lput(rB, 1);
  gread(rB, 3); lput(rA, 2);
  lput(rB, 3);
  __syncthreads();

  {
    const int n  = tid >> 2;            // output row within strip
    const int kk = (tid & 3) * 64;      // 64-k chunk (128B) per thread
    ushort* d = dst + (long)(dnoff + n0 + n) * K + k0t + kk;
    #pragma unroll
    for (int i = 0; i < 8; i++)
      *(s16x8*)(d + i * 8) = *(const s16x8*)&tileT[n][kk + i * 8];
  }
}

// fused QKV bias concat: [12][2304]
__global__ void biascat_k(const float* __restrict__ bq, const float* __restrict__ bk,
                          const float* __restrict__ bv, float* __restrict__ out)
{
  int i = blockIdx.x * 256 + threadIdx.x;
  if (i >= NLAYERS * 3 * DM) return;
  int l = i / (3 * DM), j = i % (3 * DM);
  const float* src = j < DM ? bq : (j < 2 * DM ? bk : bv);
  out[(long)l * 3 * DM + j] = src[(long)l * DM + (j % DM)];
}

// LayerNorm (f32 input), dual output; lane-contiguous vec loads
__global__ __launch_bounds__(256) void ln2_k(const float* __restrict__ X, float* __restrict__ Y,
                                             ushort* __restrict__ Yb,
                                             const float* __restrict__ g, const float* __restrict__ b)
{
  int row  = (int)((blockIdx.x * blockDim.x + threadIdx.x) >> 6);
  int lane = threadIdx.x & 63;
  const float* x = X + (long)row * DM + lane * 12;
  float v[12]; float sum = 0.f;
  #pragma unroll
  for (int j = 0; j < 3; j++) {
    f32x4 t = *(const f32x4*)(x + j * 4);
    #pragma unroll
    for (int r = 0; r < 4; r++) { v[j * 4 + r] = t[r]; sum += t[r]; }
  }
  #pragma unroll
  for (int off = 32; off; off >>= 1) sum += __shfl_xor(sum, off);
  float mean = sum * (1.0f / 768.0f);
  float var = 0.f;
  #pragma unroll
  for (int i = 0; i < 12; i++) { float d = v[i] - mean; var += d * d; }
  #pragma unroll
  for (int off = 32; off; off >>= 1) var += __shfl_xor(var, off);
  float rstd = rsqrtf(var * (1.0f / 768.0f) + 1e-5f);
  float* y = Y + (long)row * DM + lane * 12;
  ushort* yb = Yb + (long)row * DM + lane * 12;
  const float* gg = g + lane * 12;
  const float* bb = b + lane * 12;
  #pragma unroll
  for (int j = 0; j < 3; j++) {
    f32x4 go = *(const f32x4*)(gg + j * 4);
    f32x4 bo = *(const f32x4*)(bb + j * 4);
    f32x4 yo; s16x4 yh;
    #pragma unroll
    for (int r = 0; r < 4; r++) {
      float t = (v[j * 4 + r] - mean) * rstd * go[r] + bo[r];
      yo[r] = t; yh[r] = (short)f2bf(t);
    }
    *(f32x4*)(y + j * 4) = yo;
    *(s16x4*)(yb + j * 4) = yh;
  }
}

// LayerNorm over sum of two f32 partials (split-K), dual output
__global__ __launch_bounds__(256) void ln2d_k(const float* __restrict__ X0, const float* __restrict__ X1,
                                              float* __restrict__ Y, ushort* __restrict__ Yb,
                                              const float* __restrict__ g, const float* __restrict__ b)
{
  int row  = (int)((blockIdx.x * blockDim.x + threadIdx.x) >> 6);
  int lane = threadIdx.x & 63;
  const float* x0 = X0 + (long)row * DM + lane * 12;
  const float* x1 = X1 + (long)row * DM + lane * 12;
  float v[12]; float sum = 0.f;
  #pragma unroll
  for (int j = 0; j < 3; j++) {
    f32x4 a = *(const f32x4*)(x0 + j * 4);
    f32x4 c = *(const f32x4*)(x1 + j * 4);
    #pragma unroll
    for (int r = 0; r < 4; r++) {
      float t = a[r] + c[r];
      v[j * 4 + r] = t; sum += t;
    }
  }
  #pragma unroll
  for (int off = 32; off; off >>= 1) sum += __shfl_xor(sum, off);
  float mean = sum * (1.0f / 768.0f);
  float var = 0.f;
  #pragma unroll
  for (int i = 0; i < 12; i++) { float d = v[i] - mean; var += d * d; }
  #pragma unroll
  for (int off = 32; off; off >>= 1) var += __shfl_xor(var, off);
  float rstd = rsqrtf(var * (1.0f / 768.0f) + 1e-5f);
  float* y = Y + (long)row * DM + lane * 12;
  ushort* yb = Yb + (long)row * DM + lane * 12;
  const float* gg = g + lane * 12;
  const float* bb = b + lane * 12;
  #pragma unroll
  for (int j = 0; j < 3; j++) {
    f32x4 go = *(const f32x4*)(gg + j * 4);
    f32x4 bo = *(const f32x4*)(bb + j * 4);
    f32x4 yo; s16x4 yh;
    #pragma unroll
    for (int r = 0; r < 4; r++) {
      float t = (v[j * 4 + r] - mean) * rstd * go[r] + bo[r];
      yo[r] = t; yh[r] = (short)f2bf(t);
    }
    *(f32x4*)(y + j * 4) = yo;
    *(s16x4*)(yb + j * 4) = yh;
  }
}

__global__ void scan_k(const int* __restrict__ am, int* __restrict__ pos)
{
  __shared__ int buf[S_LEN];
  int t = threadIdx.x;
  buf[t] = am[t]; buf[t + 1024] = am[t + 1024];
  __syncthreads();
  for (int off = 1; off < S_LEN; off <<= 1) {
    int a0 = buf[t];
    int a1 = buf[t + 1024];
    int b0 = (t >= off) ? buf[t - off] : 0;
    int b1 = (t + 1024 >= off) ? buf[t + 1024 - off] : 0;
    __syncthreads();
    buf[t] = a0 + b0; buf[t + 1024] = a1 + b1;
    __syncthreads();
  }
  pos[t]        = buf[t] * am[t] + 1;
  pos[t + 1024] = buf[t + 1024] * am[t + 1024] + 1;
}

__global__ __launch_bounds__(256) void embed_k(const int* __restrict__ ids, const int* __restrict__ pos,
    const float* __restrict__ we, const float* __restrict__ pe, const float* __restrict__ te,
    float* __restrict__ out)
{
  int s = blockIdx.x / 3;
  int d = (blockIdx.x % 3) * 256 + threadIdx.x;
  out[(long)s * DM + d] = we[(long)ids[s] * DM + d] + pe[(long)pos[s] * DM + d] + te[d];
}

__global__ void out_k(const float* __restrict__ h, float* __restrict__ out)
{
  int i = blockIdx.x * 256 + threadIdx.x;
  if (i < DM) out[i] = h[i];
}

extern "C" void kernel_launch(void* const* d_in, const int* in_sizes, int n_in,
                              void* d_out, int out_size, void* d_ws, size_t ws_size,
                              hipStream_t stream)
{
  const int*   ids = (const int*)d_in[0];
  const int*   am  = (const int*)d_in[1];
  const float* we  = (const float*)d_in[2];
  const float* pe  = (const float*)d_in[3];
  const float* te  = (const float*)d_in[4];
  const float* eg  = (const float*)d_in[5];
  const float* eb  = (const float*)d_in[6];
  const float* Wq  = (const float*)d_in[7];
  const float* bq  = (const float*)d_in[8];
  const float* Wk  = (const float*)d_in[9];
  const float* bk  = (const float*)d_in[10];
  const float* Wv  = (const float*)d_in[11];
  const float* bv  = (const float*)d_in[12];
  const float* Wo  = (const float*)d_in[13];
  const float* bo  = (const float*)d_in[14];
  const float* g1  = (const float*)d_in[15];
  const float* b1  = (const float*)d_in[16];
  const float* W1  = (const float*)d_in[17];
  const float* c1  = (const float*)d_in[18];
  const float* W2  = (const float*)d_in[19];
  const float* c2  = (const float*)d_in[20];
  const float* g2  = (const float*)d_in[21];
  const float* b2  = (const float*)d_in[22];

  char* w = (char*)d_ws;
  float*  h    = (float*)w;  w += (size_t)S_LEN * DM * 4;
  float*  tmp  = (float*)w;  w += (size_t)S_LEN * DM * 4;
  float*  tmp2 = (float*)w;  w += (size_t)S_LEN * DM * 4;
  ushort* hb   = (ushort*)w; w += (size_t)S_LEN * DM * 2;
  ushort* qkvb = (ushort*)w; w += (size_t)S_LEN * 3 * DM * 2;
  ushort* vbT  = (ushort*)w; w += (size_t)NH * DHEAD * S_LEN * 2;
  ushort* aob  = (ushort*)w; w += (size_t)S_LEN * DM * 2;
  ushort* ffnb = (ushort*)w; w += (size_t)S_LEN * FF_DIM * 2;
  ushort* wT   = (ushort*)w; w += (size_t)NLAYERS * WSLAB * 2;
  float*  bqkv = (float*)w;  w += (size_t)NLAYERS * 3 * DM * 4;
  int*    pos  = (int*)w;

  scan_k<<<1, 1024, 0, stream>>>(am, pos);
  embed_k<<<dim3(S_LEN * 3), 256, 0, stream>>>(ids, pos, we, pe, te, tmp);
  ln2_k<<<dim3(S_LEN / 4), 256, 0, stream>>>(tmp, h, hb, eg, eb);
  biascat_k<<<dim3((NLAYERS * 3 * DM + 255) / 256), 256, 0, stream>>>(bq, bk, bv, bqkv);
  cvtall_k<<<dim3(432, NLAYERS), 256, 0, stream>>>(Wq, Wk, Wv, Wo, W1, W2, wT);

  for (int L = 0; L < NLAYERS; L++) {
    const ushort* wTL = wT + (size_t)L * WSLAB;

    // fused QKV (+ transposed V epilogue): 64x96 tile, 32 x 24 = 768 blocks
    gemm_t<0,64,96,false,true><<<dim3(768), 256, 0, stream>>>(
        hb, DM, wTL + OFF_QKVT, DM, qkvb, nullptr, 3 * DM,
        bqkv + (size_t)L * 3 * DM, nullptr, DM, vbT);

    attn_k<<<dim3(384), 256, 0, stream>>>(qkvb, vbT, am, aob);

    // O projection + residual, 64x64 split-K=2 (K=384 each): 384 x 2 blocks
    gemm_t<3,64,64,true,false><<<dim3(384, 1, 2), 256, 0, stream>>>(
        aob, DM, wTL + OFF_WOT, DM, tmp, tmp2, DM,
        bo + (size_t)L * DM, h, 384, nullptr);
    ln2d_k<<<dim3(S_LEN / 4), 256, 0, stream>>>(tmp, tmp2, h, hb,
        g1 + (size_t)L * DM, b1 + (size_t)L * DM);

    // FFN1: 64x128, 32 x 24 = 768 blocks
    gemm_t<2,64,128,false,false><<<dim3(768), 256, 0, stream>>>(
        hb, DM, wTL + OFF_W1T, DM, ffnb, nullptr, FF_DIM,
        c1 + (size_t)L * FF_DIM, nullptr, DM, nullptr);
    // FFN2 + residual, 64x64 split-K=2 (K=1536 each): 384 x 2 blocks
    gemm_t<3,64,64,true,false><<<dim3(384, 1, 2), 256, 0, stream>>>(
        ffnb, FF_DIM, wTL + OFF_W2T, FF_DIM, tmp, tmp2, DM,
        c2 + (size_t)L * DM, h, 1536, nullptr);
    ln2d_k<<<dim3(S_LEN / 4), 256, 0, stream>>>(tmp, tmp2, h, hb,
        g2 + (size_t)L * DM, b2 + (size_t)L * DM);
  }

  out_k<<<3, 256, 0, stream>>>(h, (float*)d_out);
}

// Round 17
// 1483.671 us; speedup vs baseline: 1.0184x; 1.0184x over previous
//
#include <hip/hip_runtime.h>
#include <hip/hip_bf16.h>
#include <cmath>

#define S_LEN 2048
#define DM 768
#define NH 12
#define DHEAD 64
#define FF_DIM 3072
#define NLAYERS 12
#define WIN 256

typedef __attribute__((ext_vector_type(4))) float f32x4;
typedef __attribute__((ext_vector_type(8))) short s16x8;
typedef __attribute__((ext_vector_type(4))) short s16x4;
typedef __attribute__((ext_vector_type(4))) float fragc;

// per-layer bf16 TILED-weight slab offsets (elems; all multiples of 4096)
#define OFF_QKVT 0L
#define OFF_WOT  1769472L
#define OFF_W1T  2359296L
#define OFF_W2T  4718592L
#define WSLAB    7077888L

__device__ __forceinline__ float bf2f(ushort u) {
  union { unsigned u; float f; } v; v.u = ((unsigned)u) << 16; return v.f;
}
__device__ __forceinline__ ushort f2bf(float f) {
  union { float f; unsigned u; } v; v.f = f;
  unsigned r = v.u + 0x7fffu + ((v.u >> 16) & 1u);
  return (ushort)(r >> 16);
}

typedef __attribute__((address_space(1))) const void GVp;
typedef __attribute__((address_space(3))) void LVp;
__device__ __forceinline__ void gload16(const void* g, void* l) {
  __builtin_amdgcn_global_load_lds((GVp*)g, (LVp*)l, 16, 0, 0);
}

// GEMM: BM(=64) x BN tile, BK=64, double-buffered LDS prefetch (1 barrier/
// k-step), XOR-swizzled LDS (pre-swizzled global source, linear gload_lds
// dest), 1D grid with bijective XCD swizzle. 4 waves; wave owns (BM/2)x(BN/2).
// A [M][K] bf16 row-major (K-contig). B: TILED [N/64][K/64][64][64] bf16
// (each 64x64 tile 8KB contiguous) — kt64 = K/64 tiles per n-row.
// EPI: 0 = (+bias)->bf16 ; 2 = gelu(x+bias)->bf16 ; 3 = x(+bias+res on z0)->f32
// SPLIT: gridDim.z==2, z halves of K; z=0 -> C0 (bias+res), z=1 -> C1 plain.
// VOUT: QKV only — V-tiles (nt >= 1536/BN) transpose via smem -> coalesced vbT.
template<int EPI, int BM, int BN, bool SPLIT, bool VOUT>
__global__ __launch_bounds__(256) void gemm_t(
    const ushort* __restrict__ A0, int lda,
    const ushort* __restrict__ B0, int kt64,
    void* __restrict__ C0, void* __restrict__ C1, int ldc,
    const float* __restrict__ bias0,
    const float* __restrict__ res0,
    int Kdim,                       // per-z K length
    ushort* __restrict__ vbTp)
{
  constexpr int MF = BM / 32;        // 2
  constexpr int NF = BN / 32;        // 2,3,4
  constexpr int MT = S_LEN / BM;     // 32
  __shared__ ushort As[2][BM * 64];
  __shared__ ushort Bs[2][BN * 64];

  const int tid  = threadIdx.x;
  const int lane = tid & 63;
  const int wave = tid >> 6;
  const int z    = SPLIT ? blockIdx.z : 0;
  const int koff = z * Kdim;

  const int nwg = gridDim.x;         // % 8 == 0
  const int o   = blockIdx.x;
  const int id2 = (o & 7) * (nwg >> 3) + (o >> 3);
  const int mt  = id2 % MT;
  const int nt  = id2 / MT;

  const long aoff = (long)mt * BM * lda;
  const long coff = (long)mt * BM * ldc + (long)nt * BN;
  const float* bias = bias0 ? bias0 + nt * BN : nullptr;

  fragc acc[MF][NF] = {};
  const int l15 = lane & 15;
  const int g   = lane >> 4;
  const int rx  = l15 & 7;
  const int MR0 = (wave & 1) * (BM / 2);
  const int NC0 = (wave >> 1) * (BN / 2);
  const int srow = lane >> 3;                 // 0..7 within 8-row chunk
  const int scol = ((lane & 7) ^ srow) * 8;   // pre-swizzled source col (elems)

  auto stage = [&](int buf, int k0) {
    #pragma unroll
    for (int j = 0; j < BM / 32; j++) {
      int c = wave * (BM / 32) + j;
      gload16(A0 + aoff + (long)(c * 8 + srow) * lda + k0 + scol,
              (char*)&As[buf][0] + c * 1024);
    }
    #pragma unroll
    for (int j = 0; j < BN / 32; j++) {
      int c = wave * (BN / 32) + j;
      int nbase = nt * BN + c * 8;            // 8-aligned, never crosses a 64-row tile
      long tb = (((long)(nbase >> 6) * kt64 + (k0 >> 6)) << 12) +
                ((nbase & 63) + srow) * 64 + scol;
      gload16(B0 + tb, (char*)&Bs[buf][0] + c * 1024);
    }
  };

  stage(0, koff);
  __syncthreads();
  int cur = 0;
  for (int k0 = koff; k0 < koff + Kdim; k0 += 64) {
    if (k0 + 64 < koff + Kdim) stage(cur ^ 1, k0 + 64);   // prefetch next
    s16x8 afr[MF][2], bfr[NF][2];
    #pragma unroll
    for (int ks = 0; ks < 2; ks++) {
      #pragma unroll
      for (int mi = 0; mi < MF; mi++)
        afr[mi][ks] = *(const s16x8*)((const char*)&As[cur][0] +
                      (MR0 + mi * 16 + l15) * 128 + (((ks * 4 + g) ^ rx) << 4));
      #pragma unroll
      for (int ni = 0; ni < NF; ni++)
        bfr[ni][ks] = *(const s16x8*)((const char*)&Bs[cur][0] +
                      (NC0 + ni * 16 + l15) * 128 + (((ks * 4 + g) ^ rx) << 4));
    }
    #pragma unroll
    for (int ks = 0; ks < 2; ks++)
      #pragma unroll
      for (int mi = 0; mi < MF; mi++)
        #pragma unroll
        for (int ni = 0; ni < NF; ni++)
          acc[mi][ni] = __builtin_amdgcn_mfma_f32_16x16x32_bf16(afr[mi][ks], bfr[ni][ks], acc[mi][ni], 0, 0, 0);
    __syncthreads();
    cur ^= 1;
  }

  const int rb = g * 4;

  if (VOUT && nt >= 1536 / BN) {
    // V tile: transpose in smem (alias As+Bs), then coalesced vbT stores
    ushort (*Vt)[72] = (ushort(*)[72])&As[0][0];   // BN x 72 x 2B
    #pragma unroll
    for (int mi = 0; mi < MF; mi++)
    #pragma unroll
    for (int ni = 0; ni < NF; ni++) {
      const int row0 = MR0 + mi * 16 + rb;
      const int col  = NC0 + ni * 16 + l15;
      s16x4 pk;
      #pragma unroll
      for (int r = 0; r < 4; r++) pk[r] = (short)f2bf(acc[mi][ni][r] + bias[col]);
      *(s16x4*)&Vt[col][row0] = pk;
    }
    __syncthreads();
    if (tid < BN * 2) {
      const int d  = tid >> 1;
      const int th = (tid & 1) * 32;
      ushort* gdst = vbTp + (size_t)(nt * BN - 1536 + d) * S_LEN + mt * BM + th;
      #pragma unroll
      for (int j = 0; j < 4; j++)
        *(s16x8*)(gdst + j * 8) = *(const s16x8*)&Vt[d][th + j * 8];
    }
    return;
  }

  ushort* Cb = (ushort*)C0;
  float*  Cf = (float*)(z == 0 ? C0 : C1);
  #pragma unroll
  for (int mi = 0; mi < MF; mi++)
  #pragma unroll
  for (int ni = 0; ni < NF; ni++) {
    const int row0 = MR0 + mi * 16 + rb;
    const int col  = NC0 + ni * 16 + l15;
    #pragma unroll
    for (int r = 0; r < 4; r++) {
      long ci = coff + (long)(row0 + r) * ldc + col;
      float v = acc[mi][ni][r];
      if (EPI == 0) {
        if (bias) v += bias[col];
        Cb[ci] = f2bf(v);
      } else if (EPI == 2) {
        v += bias[col];
        v = 0.5f * v * (1.0f + erff(v * 0.70710678118654752f));
        Cb[ci] = f2bf(v);
      } else {
        if (z == 0) v += bias[col] + res0[ci];
        Cf[ci] = v;
      }
    }
  }
}

// ---------------- fused sliding-window flash attention ----------------
// 1D grid 384 with XCD swizzle; 4 waves x 16 queries. K double-buffered;
// V staged for kt+1 after the PV barrier. Q frags hoisted.
__global__ __launch_bounds__(256) void attn_k(
    const ushort* __restrict__ qkvb,   // [2048][2304]
    const ushort* __restrict__ vbT,    // [12*64][2048]
    const int*    __restrict__ am,
    ushort*       __restrict__ aob)    // [2048][768]
{
  __shared__ ushort Qs[64 * 64];
  __shared__ ushort Ks[2][128 * 64];
  __shared__ ushort Vs[64 * 128];
  __shared__ ushort Ps[4][16 * 128];
  __shared__ float  ambias[768];

  const int tid  = threadIdx.x;
  const int lane = tid & 63;
  const int w    = tid >> 6;
  const int l15  = lane & 15;
  const int g    = lane >> 4;
  const int o    = blockIdx.x;
  const int id2  = (o & 7) * 48 + (o >> 3);   // 384 = 8 * 48
  const int h    = id2 >> 5;
  const int q0   = (id2 & 31) * 64;
  const int korigin = (q0 >> 8) * 256 - WIN;
  const int q    = q0 + w * 16 + l15;

  auto stageK = [&](int buf, int kt) {
    int tok0 = korigin + kt * 128;
    #pragma unroll
    for (int j = 0; j < 4; j++) {
      int c = w * 4 + j;
      int stored = c * 1024 + lane * 16;
      int row = stored >> 7;
      int within = (stored & 127) ^ ((row & 7) << 4);
      int tok = tok0 + row;
      tok = tok < 0 ? 0 : (tok > S_LEN - 1 ? S_LEN - 1 : tok);
      gload16(qkvb + (size_t)tok * 2304 + DM + h * DHEAD + (within >> 1),
              (char*)&Ks[buf][0] + stored);
    }
  };
  auto stageV = [&](int kt) {
    int tok0 = korigin + kt * 128;
    #pragma unroll
    for (int j = 0; j < 4; j++) {
      int c = w * 4 + j;
      int stored = c * 1024 + lane * 16;
      int row = stored >> 8;
      int within = (stored & 255) ^ ((row & 7) << 4);
      int tok = tok0 + (within >> 1);
      tok = tok < 0 ? 0 : (tok > S_LEN - 8 ? S_LEN - 8 : tok);
      gload16(vbT + ((size_t)h * DHEAD + row) * S_LEN + tok,
              (char*)Vs + stored);
    }
  };

  #pragma unroll
  for (int j = 0; j < 2; j++) {
    int c = w * 2 + j;
    int stored = c * 1024 + lane * 16;
    int row = stored >> 7;
    int within = (stored & 127) ^ ((row & 7) << 4);
    gload16(qkvb + (size_t)(q0 + row) * 2304 + h * DHEAD + (within >> 1),
            (char*)Qs + stored);
  }
  for (int j = tid; j < 768; j += 256) {
    int tok = korigin + j;
    bool ok = (tok >= 0) && (tok < S_LEN) && (am[tok] != 0);
    ambias[j] = ok ? 0.0f : -1e30f;
  }

  const int lo = q0 - WIN < 0 ? 0 : q0 - WIN;
  const int hi = (q0 + 63 + WIN > S_LEN - 1) ? S_LEN - 1 : q0 + 63 + WIN;
  const int kt_start = (lo - korigin) >> 7;
  const int kt_end   = (hi - korigin) >> 7;

  stageK(0, kt_start);
  stageV(kt_start);
  __syncthreads();

  s16x8 qf[2];
  #pragma unroll
  for (int ks = 0; ks < 2; ks++)
    qf[ks] = *(const s16x8*)((const char*)Qs + (w * 16 + l15) * 128 +
                             ((g * 16 + ks * 64) ^ ((l15 & 7) << 4)));

  f32x4 ot[4] = {};
  float m = -1e20f, l = 0.0f;
  int cur = 0;

  for (int kt = kt_start; kt <= kt_end; kt++) {
    if (kt < kt_end) stageK(cur ^ 1, kt + 1);

    f32x4 st[8] = {};
    __builtin_amdgcn_s_setprio(1);
    #pragma unroll
    for (int ks = 0; ks < 2; ks++) {
      #pragma unroll
      for (int mi = 0; mi < 8; mi++) {
        int row = mi * 16 + l15;
        s16x8 af = *(const s16x8*)((const char*)&Ks[cur][0] + row * 128 +
                                   ((g * 16 + ks * 64) ^ ((row & 7) << 4)));
        st[mi] = __builtin_amdgcn_mfma_f32_16x16x32_bf16(af, qf[ks], st[mi], 0, 0, 0);
      }
    }
    __builtin_amdgcn_s_setprio(0);

    float mx = -1e30f;
    float sv[8][4];
    #pragma unroll
    for (int mi = 0; mi < 8; mi++)
      #pragma unroll
      for (int r = 0; r < 4; r++) {
        int kw  = kt * 128 + mi * 16 + g * 4 + r;
        int tok = korigin + kw;
        float s = st[mi][r] * 0.125f + ambias[kw];
        bool band = (tok >= q - WIN) && (tok <= q + WIN);
        s = band ? s : -1e30f;
        sv[mi][r] = s;
        mx = fmaxf(mx, s);
      }
    mx = fmaxf(mx, __shfl_xor(mx, 16));
    mx = fmaxf(mx, __shfl_xor(mx, 32));

    float m_new = fmaxf(fmaxf(m, mx), -1e20f);
    float sf = __expf(m - m_new);
    float rs = 0.0f;
    #pragma unroll
    for (int mi = 0; mi < 8; mi++) {
      s16x4 pk;
      #pragma unroll
      for (int r = 0; r < 4; r++) {
        float p = __expf(sv[mi][r] - m_new);
        rs += p;
        pk[r] = (short)f2bf(p);
      }
      *(s16x4*)((char*)&Ps[w][0] + l15 * 256 + ((mi * 32 + g * 8) ^ ((l15 & 7) << 4))) = pk;
    }
    rs += __shfl_xor(rs, 16);
    rs += __shfl_xor(rs, 32);
    l = l * sf + rs;
    m = m_new;
    #pragma unroll
    for (int mi = 0; mi < 4; mi++)
      #pragma unroll
      for (int r = 0; r < 4; r++) ot[mi][r] *= sf;

    __syncthreads();   // B1: V(cur) + K(next) drained

    __builtin_amdgcn_s_setprio(1);
    #pragma unroll
    for (int ks = 0; ks < 4; ks++) {
      s16x8 pf = *(const s16x8*)((const char*)&Ps[w][0] + l15 * 256 +
                                 ((ks * 64 + g * 16) ^ ((l15 & 7) << 4)));
      #pragma unroll
      for (int mi = 0; mi < 4; mi++) {
        int row = mi * 16 + l15;
        s16x8 vf = *(const s16x8*)((const char*)Vs + row * 256 +
                                   ((ks * 64 + g * 16) ^ ((row & 7) << 4)));
        ot[mi] = __builtin_amdgcn_mfma_f32_16x16x32_bf16(vf, pf, ot[mi], 0, 0, 0);
      }
    }
    __builtin_amdgcn_s_setprio(0);
    __syncthreads();   // B2: all waves done with Vs

    if (kt < kt_end) stageV(kt + 1);
    cur ^= 1;
  }

  float inv = l > 0.0f ? 1.0f / l : 0.0f;
  #pragma unroll
  for (int mi = 0; mi < 4; mi++) {
    s16x4 oo;
    #pragma unroll
    for (int r = 0; r < 4; r++) oo[r] = (short)f2bf(ot[mi][r] * inv);
    *(s16x4*)(aob + (size_t)q * DM + h * DHEAD + mi * 16 + g * 4) = oo;
  }
}

// unified transpose-convert into TILED wT ([N/64][K/64][64][64], 8KB tiles).
// Each block: 64-n x 256-k strip (4 tiles). Convert phase register-pipelined
// into tileT[64][258] (129-dword row stride: both phases exactly 2-way banks);
// store phase: each WAVE writes one 8KB tile fully contiguous (lane n ->
// row n, 128B) — pure streaming writes.
// grid: (432, NLAYERS)
__global__ __launch_bounds__(256) void cvtall_k(
    const float* __restrict__ Wq, const float* __restrict__ Wk,
    const float* __restrict__ Wv, const float* __restrict__ Wo,
    const float* __restrict__ W1, const float* __restrict__ W2,
    ushort* __restrict__ wT)
{
  __shared__ ushort tileT[64][258];
  const int tid = threadIdx.x;
  const size_t L = blockIdx.y;
  int t = blockIdx.x;
  const float* src; ushort* dst; int N, K, ng, ky, dnoff = 0;
  if (t < 144) {
    int region = t / 36, tt = t % 36;
    N = DM; K = DM; ng = tt % 12; ky = tt / 12;              // 12 n x 3 ky
    src = (region == 0 ? Wq : region == 1 ? Wk : region == 2 ? Wv : Wo) + L * DM * DM;
    if (region < 3) { dst = wT + L * WSLAB + OFF_QKVT; dnoff = region * DM; }
    else            { dst = wT + L * WSLAB + OFF_WOT; }
  } else if (t < 288) {
    int tt = t - 144;
    N = FF_DIM; K = DM; ng = tt % 48; ky = tt / 48;          // 48 n x 3 ky
    src = W1 + L * DM * FF_DIM;
    dst = wT + L * WSLAB + OFF_W1T;
  } else {
    int tt = t - 288;
    N = DM; K = FF_DIM; ng = tt % 12; ky = tt / 12;          // 12 n x 12 ky
    src = W2 + L * DM * FF_DIM;
    dst = wT + L * WSLAB + OFF_W2T;
  }
  const int k0t = ky * 256;
  const int n0  = ng * 64;

  const int krel = tid >> 2;          // 0..63 source k-row within subphase
  const int nseg = (tid & 3) * 16;    // 16-col segment within 64 n

  f32x4 rA[4], rB[4];
  auto gread = [&](f32x4* r, int sub) {
    const float* s = src + (long)(k0t + sub * 64 + krel) * N + n0 + nseg;
    #pragma unroll
    for (int i = 0; i < 4; i++) r[i] = *(const f32x4*)(s + i * 4);
  };
  auto lput = [&](const f32x4* r, int sub) {
    #pragma unroll
    for (int i = 0; i < 4; i++)
      #pragma unroll
      for (int cc = 0; cc < 4; cc++)
        tileT[nseg + i * 4 + cc][sub * 64 + krel] = f2bf(r[i][cc]);
  };

  gread(rA, 0);
  gread(rB, 1); lput(rA, 0);
  gread(rA, 2); lput(rB, 1);
  gread(rB, 3); lput(rA, 2);
  lput(rB, 3);
  __syncthreads();

  {
    const int n  = tid & 63;            // row within all 4 tiles (lane id)
    const int kc = tid >> 6;            // which tile (wave id)
    const long kt64 = K >> 6;
    ushort* d = dst + ((((long)(dnoff + n0) >> 6) * kt64 + (k0t >> 6) + kc) << 12) + n * 64;
    #pragma unroll
    for (int i = 0; i < 8; i++)
      *(s16x8*)(d + i * 8) = *(const s16x8*)&tileT[n][kc * 64 + i * 8];
  }
}

// fused QKV bias concat: [12][2304]
__global__ void biascat_k(const float* __restrict__ bq, const float* __restrict__ bk,
                          const float* __restrict__ bv, float* __restrict__ out)
{
  int i = blockIdx.x * 256 + threadIdx.x;
  if (i >= NLAYERS * 3 * DM) return;
  int l = i / (3 * DM), j = i % (3 * DM);
  const float* src = j < DM ? bq : (j < 2 * DM ? bk : bv);
  out[(long)l * 3 * DM + j] = src[(long)l * DM + (j % DM)];
}

// LayerNorm (f32 input), dual output; lane-contiguous vec loads
__global__ __launch_bounds__(256) void ln2_k(const float* __restrict__ X, float* __restrict__ Y,
                                             ushort* __restrict__ Yb,
                                             const float* __restrict__ g, const float* __restrict__ b)
{
  int row  = (int)((blockIdx.x * blockDim.x + threadIdx.x) >> 6);
  int lane = threadIdx.x & 63;
  const float* x = X + (long)row * DM + lane * 12;
  float v[12]; float sum = 0.f;
  #pragma unroll
  for (int j = 0; j < 3; j++) {
    f32x4 t = *(const f32x4*)(x + j * 4);
    #pragma unroll
    for (int r = 0; r < 4; r++) { v[j * 4 + r] = t[r]; sum += t[r]; }
  }
  #pragma unroll
  for (int off = 32; off; off >>= 1) sum += __shfl_xor(sum, off);
  float mean = sum * (1.0f / 768.0f);
  float var = 0.f;
  #pragma unroll
  for (int i = 0; i < 12; i++) { float d = v[i] - mean; var += d * d; }
  #pragma unroll
  for (int off = 32; off; off >>= 1) var += __shfl_xor(var, off);
  float rstd = rsqrtf(var * (1.0f / 768.0f) + 1e-5f);
  float* y = Y + (long)row * DM + lane * 12;
  ushort* yb = Yb + (long)row * DM + lane * 12;
  const float* gg = g + lane * 12;
  const float* bb = b + lane * 12;
  #pragma unroll
  for (int j = 0; j < 3; j++) {
    f32x4 go = *(const f32x4*)(gg + j * 4);
    f32x4 bo = *(const f32x4*)(bb + j * 4);
    f32x4 yo; s16x4 yh;
    #pragma unroll
    for (int r = 0; r < 4; r++) {
      float t = (v[j * 4 + r] - mean) * rstd * go[r] + bo[r];
      yo[r] = t; yh[r] = (short)f2bf(t);
    }
    *(f32x4*)(y + j * 4) = yo;
    *(s16x4*)(yb + j * 4) = yh;
  }
}

// LayerNorm over sum of two f32 partials (split-K), dual output
__global__ __launch_bounds__(256) void ln2d_k(const float* __restrict__ X0, const float* __restrict__ X1,
                                              float* __restrict__ Y, ushort* __restrict__ Yb,
                                              const float* __restrict__ g, const float* __restrict__ b)
{
  int row  = (int)((blockIdx.x * blockDim.x + threadIdx.x) >> 6);
  int lane = threadIdx.x & 63;
  const float* x0 = X0 + (long)row * DM + lane * 12;
  const float* x1 = X1 + (long)row * DM + lane * 12;
  float v[12]; float sum = 0.f;
  #pragma unroll
  for (int j = 0; j < 3; j++) {
    f32x4 a = *(const f32x4*)(x0 + j * 4);
    f32x4 c = *(const f32x4*)(x1 + j * 4);
    #pragma unroll
    for (int r = 0; r < 4; r++) {
      float t = a[r] + c[r];
      v[j * 4 + r] = t; sum += t;
    }
  }
  #pragma unroll
  for (int off = 32; off; off >>= 1) sum += __shfl_xor(sum, off);
  float mean = sum * (1.0f / 768.0f);
  float var = 0.f;
  #pragma unroll
  for (int i = 0; i < 12; i++) { float d = v[i] - mean; var += d * d; }
  #pragma unroll
  for (int off = 32; off; off >>= 1) var += __shfl_xor(var, off);
  float rstd = rsqrtf(var * (1.0f / 768.0f) + 1e-5f);
  float* y = Y + (long)row * DM + lane * 12;
  ushort* yb = Yb + (long)row * DM + lane * 12;
  const float* gg = g + lane * 12;
  const float* bb = b + lane * 12;
  #pragma unroll
  for (int j = 0; j < 3; j++) {
    f32x4 go = *(const f32x4*)(gg + j * 4);
    f32x4 bo = *(const f32x4*)(bb + j * 4);
    f32x4 yo; s16x4 yh;
    #pragma unroll
    for (int r = 0; r < 4; r++) {
      float t = (v[j * 4 + r] - mean) * rstd * go[r] + bo[r];
      yo[r] = t; yh[r] = (short)f2bf(t);
    }
    *(f32x4*)(y + j * 4) = yo;
    *(s16x4*)(yb + j * 4) = yh;
  }
}

__global__ void scan_k(const int* __restrict__ am, int* __restrict__ pos)
{
  __shared__ int buf[S_LEN];
  int t = threadIdx.x;
  buf[t] = am[t]; buf[t + 1024] = am[t + 1024];
  __syncthreads();
  for (int off = 1; off < S_LEN; off <<= 1) {
    int a0 = buf[t];
    int a1 = buf[t + 1024];
    int b0 = (t >= off) ? buf[t - off] : 0;
    int b1 = (t + 1024 >= off) ? buf[t + 1024 - off] : 0;
    __syncthreads();
    buf[t] = a0 + b0; buf[t + 1024] = a1 + b1;
    __syncthreads();
  }
  pos[t]        = buf[t] * am[t] + 1;
  pos[t + 1024] = buf[t + 1024] * am[t + 1024] + 1;
}

__global__ __launch_bounds__(256) void embed_k(const int* __restrict__ ids, const int* __restrict__ pos,
    const float* __restrict__ we, const float* __restrict__ pe, const float* __restrict__ te,
    float* __restrict__ out)
{
  int s = blockIdx.x / 3;
  int d = (blockIdx.x % 3) * 256 + threadIdx.x;
  out[(long)s * DM + d] = we[(long)ids[s] * DM + d] + pe[(long)pos[s] * DM + d] + te[d];
}

__global__ void out_k(const float* __restrict__ h, float* __restrict__ out)
{
  int i = blockIdx.x * 256 + threadIdx.x;
  if (i < DM) out[i] = h[i];
}

extern "C" void kernel_launch(void* const* d_in, const int* in_sizes, int n_in,
                              void* d_out, int out_size, void* d_ws, size_t ws_size,
                              hipStream_t stream)
{
  const int*   ids = (const int*)d_in[0];
  const int*   am  = (const int*)d_in[1];
  const float* we  = (const float*)d_in[2];
  const float* pe  = (const float*)d_in[3];
  const float* te  = (const float*)d_in[4];
  const float* eg  = (const float*)d_in[5];
  const float* eb  = (const float*)d_in[6];
  const float* Wq  = (const float*)d_in[7];
  const float* bq  = (const float*)d_in[8];
  const float* Wk  = (const float*)d_in[9];
  const float* bk  = (const float*)d_in[10];
  const float* Wv  = (const float*)d_in[11];
  const float* bv  = (const float*)d_in[12];
  const float* Wo  = (const float*)d_in[13];
  const float* bo  = (const float*)d_in[14];
  const float* g1  = (const float*)d_in[15];
  const float* b1  = (const float*)d_in[16];
  const float* W1  = (const float*)d_in[17];
  const float* c1  = (const float*)d_in[18];
  const float* W2  = (const float*)d_in[19];
  const float* c2  = (const float*)d_in[20];
  const float* g2  = (const float*)d_in[21];
  const float* b2  = (const float*)d_in[22];

  char* w = (char*)d_ws;
  float*  h    = (float*)w;  w += (size_t)S_LEN * DM * 4;
  float*  tmp  = (float*)w;  w += (size_t)S_LEN * DM * 4;
  float*  tmp2 = (float*)w;  w += (size_t)S_LEN * DM * 4;
  ushort* hb   = (ushort*)w; w += (size_t)S_LEN * DM * 2;
  ushort* qkvb = (ushort*)w; w += (size_t)S_LEN * 3 * DM * 2;
  ushort* vbT  = (ushort*)w; w += (size_t)NH * DHEAD * S_LEN * 2;
  ushort* aob  = (ushort*)w; w += (size_t)S_LEN * DM * 2;
  ushort* ffnb = (ushort*)w; w += (size_t)S_LEN * FF_DIM * 2;
  ushort* wT   = (ushort*)w; w += (size_t)NLAYERS * WSLAB * 2;
  float*  bqkv = (float*)w;  w += (size_t)NLAYERS * 3 * DM * 4;
  int*    pos  = (int*)w;

  scan_k<<<1, 1024, 0, stream>>>(am, pos);
  embed_k<<<dim3(S_LEN * 3), 256, 0, stream>>>(ids, pos, we, pe, te, tmp);
  ln2_k<<<dim3(S_LEN / 4), 256, 0, stream>>>(tmp, h, hb, eg, eb);
  biascat_k<<<dim3((NLAYERS * 3 * DM + 255) / 256), 256, 0, stream>>>(bq, bk, bv, bqkv);
  cvtall_k<<<dim3(432, NLAYERS), 256, 0, stream>>>(Wq, Wk, Wv, Wo, W1, W2, wT);

  for (int L = 0; L < NLAYERS; L++) {
    const ushort* wTL = wT + (size_t)L * WSLAB;

    // fused QKV (+ transposed V epilogue): 64x96 tile, 32 x 24 = 768 blocks
    gemm_t<0,64,96,false,true><<<dim3(768), 256, 0, stream>>>(
        hb, DM, wTL + OFF_QKVT, 12, qkvb, nullptr, 3 * DM,
        bqkv + (size_t)L * 3 * DM, nullptr, DM, vbT);

    attn_k<<<dim3(384), 256, 0, stream>>>(qkvb, vbT, am, aob);

    // O projection + residual, 64x64 split-K=2 (K=384 each): 384 x 2 blocks
    gemm_t<3,64,64,true,false><<<dim3(384, 1, 2), 256, 0, stream>>>(
        aob, DM, wTL + OFF_WOT, 12, tmp, tmp2, DM,
        bo + (size_t)L * DM, h, 384, nullptr);
    ln2d_k<<<dim3(S_LEN / 4), 256, 0, stream>>>(tmp, tmp2, h, hb,
        g1 + (size_t)L * DM, b1 + (size_t)L * DM);

    // FFN1: 64x128, 32 x 24 = 768 blocks
    gemm_t<2,64,128,false,false><<<dim3(768), 256, 0, stream>>>(
        hb, DM, wTL + OFF_W1T, 12, ffnb, nullptr, FF_DIM,
        c1 + (size_t)L * FF_DIM, nullptr, DM, nullptr);
    // FFN2 + residual, 64x64 split-K=2 (K=1536 each): 384 x 2 blocks
    gemm_t<3,64,64,true,false><<<dim3(384, 1, 2), 256, 0, stream>>>(
        ffnb, FF_DIM, wTL + OFF_W2T, 48, tmp, tmp2, DM,
        c2 + (size_t)L * DM, h, 1536, nullptr);
    ln2d_k<<<dim3(S_LEN / 4), 256, 0, stream>>>(tmp, tmp2, h, hb,
        g2 + (size_t)L * DM, b2 + (size_t)L * DM);
  }

  out_k<<<3, 256, 0, stream>>>(h, (float*)d_out);
}